// Round 2
// baseline (400.848 us; speedup 1.0000x reference)
//
#include <hip/hip_runtime.h>
#include <hip/hip_bf16.h>

// Problem constants (from reference): B=16, F=128, N=2048
#define B_ 16
#define F_ 128
#define N_ 2048
#define M_TOT (B_ * F_ * N_)   // 4,194,304 elements in emb_in

// ---------------------------------------------------------------------------
// Kernel 1 (fused): one pass over emb.
//   d[b,n]      = sum_f v[f] * emb[b,f,n]          (UNNORMALIZED dot)
//   partials[blk] = (sum x, sum x^2) over the 128x128 elements this block reads
// grid = 256 blocks x 128 threads: one thread per column (b,n); lanes hit
// consecutive n so every f-step is a fully coalesced 256B wave load.
// Each element of emb is read exactly once (covers the std reduction too).
// ---------------------------------------------------------------------------
__global__ __launch_bounds__(128) void k_fused(const float* __restrict__ emb,
                                               const float* __restrict__ v,
                                               float* __restrict__ d,
                                               float* __restrict__ partials) {
    __shared__ float vs[F_];
    int tid = threadIdx.x;          // 0..127 == f index
    vs[tid] = v[tid];
    __syncthreads();

    int col = blockIdx.x * 128 + tid;   // 0 .. B_*N_-1
    int b = col >> 11;                  // / N_
    int n = col & (N_ - 1);             // % N_
    const float* base = emb + (size_t)b * F_ * N_ + n;

    float acc = 0.f, s = 0.f, q = 0.f;
    #pragma unroll 16
    for (int f = 0; f < F_; ++f) {
        float x = base[(size_t)f * N_];
        acc += vs[f] * x;
        s += x;
        q += x * x;
    }
    d[col] = acc;

    // wave64 shuffle reduce of the std partials
    #pragma unroll
    for (int off = 32; off > 0; off >>= 1) {
        s += __shfl_down(s, off);
        q += __shfl_down(q, off);
    }
    __shared__ float ls[2], lq[2];      // 128 threads = 2 waves
    int wave = tid >> 6;
    if ((tid & 63) == 0) { ls[wave] = s; lq[wave] = q; }
    __syncthreads();
    if (tid == 0) {
        partials[2 * blockIdx.x]     = ls[0] + ls[1];
        partials[2 * blockIdx.x + 1] = lq[0] + lq[1];
    }
}

// ---------------------------------------------------------------------------
// Kernel 2: reduce 256 partial pairs -> inv_std (one tiny block)
// ---------------------------------------------------------------------------
__global__ __launch_bounds__(256) void k_finalize(const float* __restrict__ partials,
                                                  float* __restrict__ inv_std) {
    int tid = threadIdx.x;              // exactly one pair per thread (256 blocks)
    float s = partials[2 * tid];
    float q = partials[2 * tid + 1];
    #pragma unroll
    for (int off = 32; off > 0; off >>= 1) {
        s += __shfl_down(s, off);
        q += __shfl_down(q, off);
    }
    __shared__ float ls[4], lq[4];
    int wave = tid >> 6;
    if ((tid & 63) == 0) { ls[wave] = s; lq[wave] = q; }
    __syncthreads();
    if (tid == 0) {
        float S = ls[0] + ls[1] + ls[2] + ls[3];
        float Q = lq[0] + lq[1] + lq[2] + lq[3];
        float mean = S / (float)M_TOT;
        // unbiased variance over all elements (torch .std(), ddof=1)
        float var = (Q - S * mean) / (float)(M_TOT - 1);
        inv_std[0] = rsqrtf(var);
    }
}

// ---------------------------------------------------------------------------
// Kernel 3: out[b,i,j] = sigmoid(inv_std*(d_i + d_j) + bias)
// 4 rows per block (8192 blocks x 256 thr). Scaled row tjs = inv_std*d[b,:]
// staged in LDS once per block, reused for 4 rows -> per element: 1 add +
// sigmoid + float4 store. HBM traffic ~= pure 256 MiB write stream.
// ---------------------------------------------------------------------------
__device__ __forceinline__ float fast_sigmoid(float x) {
    float e = __expf(-x);
    return __builtin_amdgcn_rcpf(1.0f + e);
}

__global__ __launch_bounds__(256) void k_out(const float* __restrict__ d,
                                             const float* __restrict__ inv_std_p,
                                             const float* __restrict__ bias,
                                             float* __restrict__ out) {
    __shared__ float tjs[N_];           // 8 KB
    int blk = blockIdx.x;               // 0..8191
    int b  = blk >> 9;                  // 512 blocks per batch image
    int i0 = (blk & 511) * 4;           // first of this block's 4 rows
    int tid = threadIdx.x;

    float is = inv_std_p[0];
    float bb = bias[0];
    const float* db = d + ((size_t)b << 11);

    #pragma unroll
    for (int k = 0; k < 8; ++k) {
        int j = tid + k * 256;
        tjs[j] = is * db[j];
    }
    __syncthreads();

    float a[4];
    #pragma unroll
    for (int r = 0; r < 4; ++r) a[r] = tjs[i0 + r] + bb;

    float4* o4 = (float4*)(out + ((size_t)b * N_ + i0) * N_);  // row i0 base

    #pragma unroll
    for (int r = 0; r < 4; ++r) {
        #pragma unroll
        for (int k = 0; k < 2; ++k) {
            int j4 = tid + k * 256;                 // float4 slot in the row
            float4 tj = *(const float4*)&tjs[j4 * 4];
            float4 rr;
            rr.x = fast_sigmoid(a[r] + tj.x);
            rr.y = fast_sigmoid(a[r] + tj.y);
            rr.z = fast_sigmoid(a[r] + tj.z);
            rr.w = fast_sigmoid(a[r] + tj.w);
            o4[(size_t)r * 512 + j4] = rr;
        }
    }
}

// ---------------------------------------------------------------------------
// Launch: 3 dispatches, all on `stream` (graph-safe, no mallocs/syncs)
// ---------------------------------------------------------------------------
extern "C" void kernel_launch(void* const* d_in, const int* in_sizes, int n_in,
                              void* d_out, int out_size, void* d_ws, size_t ws_size,
                              hipStream_t stream) {
    // inputs in setup_inputs() order: adj_in (unused), emb_in, v, b
    const float* emb  = (const float*)d_in[1];
    const float* v    = (const float*)d_in[2];
    const float* bias = (const float*)d_in[3];
    float* out = (float*)d_out;

    // workspace layout (floats): d [0..32767], partials [32768..33279], inv_std [33280]
    float* wsf      = (float*)d_ws;
    float* d        = wsf;
    float* partials = wsf + 32768;
    float* inv_std  = wsf + 32768 + 512;

    k_fused<<<256, 128, 0, stream>>>(emb, v, d, partials);
    k_finalize<<<1, 256, 0, stream>>>(partials, inv_std);
    k_out<<<8192, 256, 0, stream>>>(d, inv_std, bias, out);
}

// Round 3
// 399.114 us; speedup vs baseline: 1.0043x; 1.0043x over previous
//
#include <hip/hip_runtime.h>
#include <hip/hip_bf16.h>

// Problem constants (from reference): B=16, F=128, N=2048
#define B_ 16
#define F_ 128
#define N_ 2048
#define M_TOT (B_ * F_ * N_)   // 4,194,304 elements in emb_in

// ---------------------------------------------------------------------------
// Kernel 1 (fused): one pass over emb.
//   d[b,n]        = sum_f v[f] * emb[b,f,n]       (UNNORMALIZED dot)
//   partials[blk] = (sum x, sum x^2) over the 128x128 elements this block reads
// grid = 256 blocks x 128 threads: one thread per column (b,n); lanes hit
// consecutive n so every f-step is a fully coalesced 256B wave load.
// Each element of emb is read exactly once (covers the std reduction too).
// ---------------------------------------------------------------------------
__global__ __launch_bounds__(128) void k_fused(const float* __restrict__ emb,
                                               const float* __restrict__ v,
                                               float* __restrict__ d,
                                               float* __restrict__ partials) {
    __shared__ float vs[F_];
    int tid = threadIdx.x;          // 0..127 == f index
    vs[tid] = v[tid];
    __syncthreads();

    int col = blockIdx.x * 128 + tid;   // 0 .. B_*N_-1
    int b = col >> 11;                  // / N_
    int n = col & (N_ - 1);             // % N_
    const float* base = emb + (size_t)b * F_ * N_ + n;

    float acc = 0.f, s = 0.f, q = 0.f;
    #pragma unroll 16
    for (int f = 0; f < F_; ++f) {
        float x = base[(size_t)f * N_];
        acc += vs[f] * x;
        s += x;
        q += x * x;
    }
    d[col] = acc;

    // wave64 shuffle reduce of the std partials
    #pragma unroll
    for (int off = 32; off > 0; off >>= 1) {
        s += __shfl_down(s, off);
        q += __shfl_down(q, off);
    }
    __shared__ float ls[2], lq[2];      // 128 threads = 2 waves
    int wave = tid >> 6;
    if ((tid & 63) == 0) { ls[wave] = s; lq[wave] = q; }
    __syncthreads();
    if (tid == 0) {
        partials[2 * blockIdx.x]     = ls[0] + ls[1];
        partials[2 * blockIdx.x + 1] = lq[0] + lq[1];
    }
}

// ---------------------------------------------------------------------------
// Kernel 2: out[b,i,j] = sigmoid(is*d_i + is*d_j + bias)
// Each block redundantly reduces the 256 partial pairs (512 L2-hot floats)
// to inv_std — saves a separate finalize dispatch. Raw d row staged in LDS
// (no scale needed -> shares one barrier with the partials reduce); scale is
// folded into the per-element FMA. 4 rows/block, 8192 blocks x 256 thr,
// 2 float4 stores per row per thread. HBM traffic ~= pure 256 MiB writes.
// ---------------------------------------------------------------------------
__device__ __forceinline__ float fast_sigmoid(float x) {
    float e = __expf(-x);
    return __builtin_amdgcn_rcpf(1.0f + e);
}

__global__ __launch_bounds__(256) void k_out(const float* __restrict__ d,
                                             const float* __restrict__ partials,
                                             const float* __restrict__ bias,
                                             float* __restrict__ out) {
    __shared__ float tjs[N_];           // 8 KB raw d row
    __shared__ float ls[4], lq[4];
    int blk = blockIdx.x;               // 0..8191
    int b  = blk >> 9;                  // 512 blocks per batch image
    int i0 = (blk & 511) * 4;           // first of this block's 4 rows
    int tid = threadIdx.x;

    // --- per-block inv_std recompute: one partial pair per thread ---
    float s = partials[2 * tid];
    float q = partials[2 * tid + 1];
    #pragma unroll
    for (int off = 32; off > 0; off >>= 1) {
        s += __shfl_down(s, off);
        q += __shfl_down(q, off);
    }
    if ((tid & 63) == 0) { ls[tid >> 6] = s; lq[tid >> 6] = q; }

    // --- stage raw d row while the reduce lands (same barrier) ---
    const float* db = d + ((size_t)b << 11);
    #pragma unroll
    for (int k = 0; k < 8; ++k) {
        int j = tid + k * 256;
        tjs[j] = db[j];
    }
    __syncthreads();

    // every thread finishes the combine itself (no second barrier)
    float S = ls[0] + ls[1] + ls[2] + ls[3];
    float Q = lq[0] + lq[1] + lq[2] + lq[3];
    float mean = S / (float)M_TOT;
    float var  = (Q - S * mean) / (float)(M_TOT - 1);  // unbiased (ddof=1)
    float is   = rsqrtf(var);
    float bb   = bias[0];

    float a[4];
    #pragma unroll
    for (int r = 0; r < 4; ++r) a[r] = fmaf(is, tjs[i0 + r], bb);

    float4* o4 = (float4*)(out + ((size_t)b * N_ + i0) * N_);  // row i0 base

    #pragma unroll
    for (int r = 0; r < 4; ++r) {
        #pragma unroll
        for (int k = 0; k < 2; ++k) {
            int j4 = tid + k * 256;                 // float4 slot in the row
            float4 tj = *(const float4*)&tjs[j4 * 4];
            float4 rr;
            rr.x = fast_sigmoid(fmaf(is, tj.x, a[r]));
            rr.y = fast_sigmoid(fmaf(is, tj.y, a[r]));
            rr.z = fast_sigmoid(fmaf(is, tj.z, a[r]));
            rr.w = fast_sigmoid(fmaf(is, tj.w, a[r]));
            o4[(size_t)r * 512 + j4] = rr;
        }
    }
}

// ---------------------------------------------------------------------------
// Launch: 2 dispatches, all on `stream` (graph-safe, no mallocs/syncs)
// ---------------------------------------------------------------------------
extern "C" void kernel_launch(void* const* d_in, const int* in_sizes, int n_in,
                              void* d_out, int out_size, void* d_ws, size_t ws_size,
                              hipStream_t stream) {
    // inputs in setup_inputs() order: adj_in (unused), emb_in, v, b
    const float* emb  = (const float*)d_in[1];
    const float* v    = (const float*)d_in[2];
    const float* bias = (const float*)d_in[3];
    float* out = (float*)d_out;

    // workspace layout (floats): d [0..32767], partials [32768..33279]
    float* wsf      = (float*)d_ws;
    float* d        = wsf;
    float* partials = wsf + 32768;

    k_fused<<<256, 128, 0, stream>>>(emb, v, d, partials);
    k_out<<<8192, 256, 0, stream>>>(d, partials, bias, out);
}